// Round 7
// baseline (159.598 us; speedup 1.0000x reference)
//
#include <hip/hip_runtime.h>
#include <math.h>

#define TWO_PI_F 6.28318530717958647692f
#define PI_F     3.14159265358979323846f

__device__ __forceinline__ float warp_sum(float s) {
    #pragma unroll
    for (int off = 32; off; off >>= 1) s += __shfl_xor(s, off, 64);
    return s;
}
__device__ __forceinline__ float warp_max(float m) {
    #pragma unroll
    for (int off = 32; off; off >>= 1) m = fmaxf(m, __shfl_xor(m, off, 64));
    return m;
}

__device__ __forceinline__ float edge_wrap(float a, float b) {
    float d = fabsf(a - b);
    d = fmodf(d, TWO_PI_F);
    return (d > PI_F) ? (TWO_PI_F - d) : d;
}

__device__ __forceinline__ float sum4e(float4 v) {
    return __expf(v.x) + __expf(v.y) + __expf(v.z) + __expf(v.w);
}

// Generic CE fallback (C > 1024): two passes with max subtraction.
__device__ float ce_row_generic(const float* __restrict__ rowp, int C, int lane, int t) {
    const float4* row4 = (const float4*)rowp;
    const int nf4 = C >> 2;
    const float tv = rowp[t];
    float m = -INFINITY;
    for (int j = lane; j < nf4; j += 64) {
        float4 x = row4[j];
        m = fmaxf(m, fmaxf(fmaxf(x.x, x.y), fmaxf(x.z, x.w)));
    }
    const int remBase = nf4 << 2;
    if (remBase + lane < C) m = fmaxf(m, rowp[remBase + lane]);
    m = warp_max(m);
    float s = 0.0f;
    for (int j = lane; j < nf4; j += 64) {
        float4 x = row4[j];
        s += __expf(x.x - m) + __expf(x.y - m) + __expf(x.z - m) + __expf(x.w - m);
    }
    if (remBase + lane < C) s += __expf(rowp[remBase + lane] - m);
    s = warp_sum(s);
    return m + __logf(s) - tv;
}

// Stage 1: fused CE + resonance; one plain partial store per block (NO atomics:
// single-address atomicAdd from ~4.6K blocks measured ~35us of serialization).
//   blocks [0, res_blocks)          : 4 edges/thread, int4 index loads
//   blocks [res_blocks, +ce_blocks) : ONE CE row per wave (many thin waves ->
//                                     max independent load streams per CU; the
//                                     2-rows/wave variants measured SLOWER).
//   CE math: direct logsumexp, no max pass (N(0,1) logits, fp32-safe;
//   verified absmax 0.0 in R6). Padding slots use __expf(-INF) = 0.
__global__ __launch_bounds__(256) void fused_kernel(
    const float* __restrict__ outputs,
    const int*   __restrict__ targets,
    const float* __restrict__ phase,
    const int*   __restrict__ esrc,
    const int*   __restrict__ edst,
    int B, int C, int N, int E,
    int res_blocks,
    float invB, float scaleE,
    float* __restrict__ ws)
{
    __shared__ float part[4];
    const int lane = threadIdx.x & 63;
    const int wave = threadIdx.x >> 6;

    float wsum = 0.0f;

    if ((int)blockIdx.x < res_blocks) {
        const int base = (blockIdx.x * 256 + threadIdx.x) * 4;
        float d = 0.0f;
        if (base + 3 < E) {
            const int4 s4 = *(const int4*)(esrc + base);
            const int4 t4 = *(const int4*)(edst + base);
            const float a0 = phase[(size_t)s4.x * (size_t)N + (size_t)t4.x];
            const float b0 = phase[(size_t)t4.x * (size_t)N + (size_t)s4.x];
            const float a1 = phase[(size_t)s4.y * (size_t)N + (size_t)t4.y];
            const float b1 = phase[(size_t)t4.y * (size_t)N + (size_t)s4.y];
            const float a2 = phase[(size_t)s4.z * (size_t)N + (size_t)t4.z];
            const float b2 = phase[(size_t)t4.z * (size_t)N + (size_t)s4.z];
            const float a3 = phase[(size_t)s4.w * (size_t)N + (size_t)t4.w];
            const float b3 = phase[(size_t)t4.w * (size_t)N + (size_t)s4.w];
            d = edge_wrap(a0, b0) + edge_wrap(a1, b1)
              + edge_wrap(a2, b2) + edge_wrap(a3, b3);
        } else {
            for (int i = base; i < E; i++) {
                const int s = esrc[i], t = edst[i];
                d += edge_wrap(phase[(size_t)s * (size_t)N + (size_t)t],
                               phase[(size_t)t * (size_t)N + (size_t)s]);
            }
        }
        d = warp_sum(d);
        if (lane == 0) wsum = d * scaleE;
    } else {
        const int row = ((int)blockIdx.x - res_blocks) * 4 + wave;
        const int nf4 = C >> 2;
        if (row < B) {
            if (nf4 <= 256) {
                // ---- fast path: row in 4 named float4 regs + tv, one sum ----
                const float* rowp = outputs + (size_t)row * (size_t)C;
                const float4* row4 = (const float4*)rowp;
                const float4 NEG = make_float4(-INFINITY, -INFINITY, -INFINITY, -INFINITY);
                const int t = targets[row];                 // scalar, issue first
                const int j0 = lane, j1 = lane + 64, j2 = lane + 128, j3 = lane + 192;
                float4 v0 = (j0 < nf4) ? row4[j0] : NEG;
                float4 v1 = (j1 < nf4) ? row4[j1] : NEG;
                float4 v2 = (j2 < nf4) ? row4[j2] : NEG;
                float4 v3 = (j3 < nf4) ? row4[j3] : NEG;
                const int remBase = nf4 << 2;
                float tail = (remBase + lane < C) ? rowp[remBase + lane] : -INFINITY;
                const float tv = rowp[t];                   // broadcast load

                float s = sum4e(v0) + sum4e(v1) + sum4e(v2) + sum4e(v3)
                        + __expf(tail);
                s = warp_sum(s);
                if (lane == 0) wsum = (__logf(s) - tv) * invB;
            } else {
                const float c = ce_row_generic(outputs + (size_t)row * (size_t)C,
                                               C, lane, targets[row]);
                if (lane == 0) wsum = c * invB;
            }
        }
    }

    if (lane == 0) part[wave] = wsum;
    __syncthreads();
    if (threadIdx.x == 0)
        ws[blockIdx.x] = part[0] + part[1] + part[2] + part[3];
}

// Stage 2: one block reduces all partials.
__global__ __launch_bounds__(256) void reduce_kernel(
    const float* __restrict__ ws, int P, float* __restrict__ out)
{
    float s = 0.0f;
    for (int i = threadIdx.x; i < P; i += 256)
        s += ws[i];
    s = warp_sum(s);
    __shared__ float part[4];
    if ((threadIdx.x & 63) == 0) part[threadIdx.x >> 6] = s;
    __syncthreads();
    if (threadIdx.x == 0)
        out[0] = part[0] + part[1] + part[2] + part[3];
}

extern "C" void kernel_launch(void* const* d_in, const int* in_sizes, int n_in,
                              void* d_out, int out_size, void* d_ws, size_t ws_size,
                              hipStream_t stream) {
    const float* outputs = (const float*)d_in[0];
    const int*   targets = (const int*)d_in[1];
    const float* phase   = (const float*)d_in[2];
    const int*   esrc    = (const int*)d_in[3];
    const int*   edst    = (const int*)d_in[4];

    const int B = in_sizes[1];
    const int C = in_sizes[0] / B;
    const int E = in_sizes[3];
    int N = 1;
    while ((long long)N * (long long)N < (long long)in_sizes[2]) N++;

    const int res_blocks = (E + 1023) / 1024;        // 128 (4 edges/thread)
    const int ce_blocks  = (B + 3) / 4;              // 4096 (1 row/wave)
    const int grid = res_blocks + ce_blocks;         // 4224 partials

    float* ws = (float*)d_ws;

    fused_kernel<<<grid, 256, 0, stream>>>(outputs, targets, phase, esrc, edst,
                                           B, C, N, E, res_blocks,
                                           1.0f / (float)B, 0.1f / (float)E,
                                           ws);
    reduce_kernel<<<1, 256, 0, stream>>>(ws, grid, (float*)d_out);
}

// Round 8
// 148.596 us; speedup vs baseline: 1.0740x; 1.0740x over previous
//
#include <hip/hip_runtime.h>
#include <math.h>

#define TWO_PI_F 6.28318530717958647692f
#define PI_F     3.14159265358979323846f

__device__ __forceinline__ float warp_sum(float s) {
    #pragma unroll
    for (int off = 32; off; off >>= 1) s += __shfl_xor(s, off, 64);
    return s;
}
__device__ __forceinline__ float warp_max(float m) {
    #pragma unroll
    for (int off = 32; off; off >>= 1) m = fmaxf(m, __shfl_xor(m, off, 64));
    return m;
}

__device__ __forceinline__ float edge_wrap(float a, float b) {
    float d = fabsf(a - b);
    d = fmodf(d, TWO_PI_F);
    return (d > PI_F) ? (TWO_PI_F - d) : d;
}

// -log_softmax(row)[t], wave-uniform return value.
__device__ __forceinline__ float ce_row(const float* __restrict__ rowp,
                                        int C, int lane, int t) {
    const float4* row4 = (const float4*)rowp;
    const int nf4 = C >> 2;
    const float tv = rowp[t];                 // same addr all lanes -> broadcast
    float m, s;
    if (nf4 <= 256) {
        // whole row in 4 named float4 regs/lane (no arrays -> no LDS demotion)
        const float4 NEG = make_float4(-INFINITY, -INFINITY, -INFINITY, -INFINITY);
        const int j0 = lane, j1 = lane + 64, j2 = lane + 128, j3 = lane + 192;
        float4 v0 = (j0 < nf4) ? row4[j0] : NEG;
        float4 v1 = (j1 < nf4) ? row4[j1] : NEG;
        float4 v2 = (j2 < nf4) ? row4[j2] : NEG;
        float4 v3 = (j3 < nf4) ? row4[j3] : NEG;
        const int remBase = nf4 << 2;
        float tail = (remBase + lane < C) ? rowp[remBase + lane] : -INFINITY;

        m = tail;
        m = fmaxf(m, fmaxf(fmaxf(v0.x, v0.y), fmaxf(v0.z, v0.w)));
        m = fmaxf(m, fmaxf(fmaxf(v1.x, v1.y), fmaxf(v1.z, v1.w)));
        m = fmaxf(m, fmaxf(fmaxf(v2.x, v2.y), fmaxf(v2.z, v2.w)));
        m = fmaxf(m, fmaxf(fmaxf(v3.x, v3.y), fmaxf(v3.z, v3.w)));
        m = warp_max(m);

        s  = __expf(v0.x - m) + __expf(v0.y - m) + __expf(v0.z - m) + __expf(v0.w - m);
        s += __expf(v1.x - m) + __expf(v1.y - m) + __expf(v1.z - m) + __expf(v1.w - m);
        s += __expf(v2.x - m) + __expf(v2.y - m) + __expf(v2.z - m) + __expf(v2.w - m);
        s += __expf(v3.x - m) + __expf(v3.y - m) + __expf(v3.z - m) + __expf(v3.w - m);
        s += __expf(tail - m);
        s = warp_sum(s);
    } else {
        // generic fallback: two passes, re-read global (L2-hot)
        m = -INFINITY;
        for (int j = lane; j < nf4; j += 64) {
            float4 x = row4[j];
            m = fmaxf(m, fmaxf(fmaxf(x.x, x.y), fmaxf(x.z, x.w)));
        }
        const int remBase = nf4 << 2;
        if (remBase + lane < C) m = fmaxf(m, rowp[remBase + lane]);
        m = warp_max(m);
        s = 0.0f;
        for (int j = lane; j < nf4; j += 64) {
            float4 x = row4[j];
            s += __expf(x.x - m) + __expf(x.y - m) + __expf(x.z - m) + __expf(x.w - m);
        }
        if (remBase + lane < C) s += __expf(rowp[remBase + lane] - m);
        s = warp_sum(s);
    }
    return m + __logf(s) - tv;
}

// Stage 1: fused CE + resonance; one plain partial store per block.
__global__ __launch_bounds__(256) void fused_kernel(
    const float* __restrict__ outputs,
    const int*   __restrict__ targets,
    const float* __restrict__ phase,
    const int*   __restrict__ esrc,
    const int*   __restrict__ edst,
    int B, int C, int N, int E,
    int res_blocks,
    float invB, float scaleE,
    float* __restrict__ ws)
{
    __shared__ float part[4];
    const int lane = threadIdx.x & 63;
    const int wave = threadIdx.x >> 6;

    float wsum = 0.0f;                       // lane0-of-wave contribution (pre-scaled)

    if ((int)blockIdx.x < res_blocks) {
        // ---------------- resonance path: one thread per edge ----------------
        const int i = blockIdx.x * blockDim.x + threadIdx.x;
        float d = 0.0f;
        if (i < E) {
            const int s = esrc[i];
            const int t = edst[i];
            const float a = phase[(size_t)s * (size_t)N + (size_t)t];
            const float b = phase[(size_t)t * (size_t)N + (size_t)s];
            d = fabsf(a - b);
            d = fmodf(d, TWO_PI_F);
            if (d > PI_F) d = TWO_PI_F - d;
        }
        #pragma unroll
        for (int off = 32; off; off >>= 1)
            d += __shfl_xor(d, off, 64);
        if (lane == 0) wsum = d * scaleE;
    } else {
        // ---------------- CE path: one wave per row --------------------------
        const int row = (blockIdx.x - res_blocks) * 4 + wave;
        if (row < B) {
            const int t = targets[row];
            const float c = ce_row(outputs + (size_t)row * (size_t)C, C, lane, t);
            if (lane == 0) wsum = c * invB;
        }
    }

    if (lane == 0) part[wave] = wsum;
    __syncthreads();
    if (threadIdx.x == 0)
        ws[blockIdx.x] = part[0] + part[1] + part[2] + part[3];   // plain store
}

// Stage 2: single block reduces all partials and writes the scalar output.
__global__ __launch_bounds__(256) void reduce_kernel(
    const float* __restrict__ ws, int P, float* __restrict__ out)
{
    float s = 0.0f;
    for (int i = threadIdx.x; i < P; i += 256)
        s += ws[i];
    s = warp_sum(s);
    __shared__ float part[4];
    if ((threadIdx.x & 63) == 0) part[threadIdx.x >> 6] = s;
    __syncthreads();
    if (threadIdx.x == 0)
        out[0] = part[0] + part[1] + part[2] + part[3];
}

extern "C" void kernel_launch(void* const* d_in, const int* in_sizes, int n_in,
                              void* d_out, int out_size, void* d_ws, size_t ws_size,
                              hipStream_t stream) {
    const float* outputs = (const float*)d_in[0];
    const int*   targets = (const int*)d_in[1];
    const float* phase   = (const float*)d_in[2];
    const int*   esrc    = (const int*)d_in[3];
    const int*   edst    = (const int*)d_in[4];

    const int B = in_sizes[1];
    const int C = in_sizes[0] / B;
    const int E = in_sizes[3];
    int N = 1;
    while ((long long)N * (long long)N < (long long)in_sizes[2]) N++;

    const int res_blocks = (E + 255) / 256;          // 512
    const int ce_blocks  = (B + 3) / 4;              // 4096
    const int grid = res_blocks + ce_blocks;         // 4608 partials

    float* ws = (float*)d_ws;

    fused_kernel<<<grid, 256, 0, stream>>>(outputs, targets, phase, esrc, edst,
                                           B, C, N, E, res_blocks,
                                           1.0f / (float)B, 0.1f / (float)E,
                                           ws);
    reduce_kernel<<<1, 256, 0, stream>>>(ws, grid, (float*)d_out);
}

// Round 9
// 145.452 us; speedup vs baseline: 1.0973x; 1.0216x over previous
//
#include <hip/hip_runtime.h>
#include <math.h>

#define TWO_PI_F 6.28318530717958647692f
#define PI_F     3.14159265358979323846f

typedef float f32x4 __attribute__((ext_vector_type(4)));

__device__ __forceinline__ float warp_sum(float s) {
    #pragma unroll
    for (int off = 32; off; off >>= 1) s += __shfl_xor(s, off, 64);
    return s;
}
__device__ __forceinline__ float warp_max(float m) {
    #pragma unroll
    for (int off = 32; off; off >>= 1) m = fmaxf(m, __shfl_xor(m, off, 64));
    return m;
}

__device__ __forceinline__ float max4(f32x4 v) {
    return fmaxf(fmaxf(v.x, v.y), fmaxf(v.z, v.w));
}

// Generic CE fallback (C > 1024): two passes with max subtraction.
__device__ float ce_row_generic(const float* __restrict__ rowp, int C, int lane, int t) {
    const float4* row4 = (const float4*)rowp;
    const int nf4 = C >> 2;
    const float tv = rowp[t];
    float m = -INFINITY;
    for (int j = lane; j < nf4; j += 64) {
        float4 x = row4[j];
        m = fmaxf(m, fmaxf(fmaxf(x.x, x.y), fmaxf(x.z, x.w)));
    }
    const int remBase = nf4 << 2;
    if (remBase + lane < C) m = fmaxf(m, rowp[remBase + lane]);
    m = warp_max(m);
    float s = 0.0f;
    for (int j = lane; j < nf4; j += 64) {
        float4 x = row4[j];
        s += __expf(x.x - m) + __expf(x.y - m) + __expf(x.z - m) + __expf(x.w - m);
    }
    if (remBase + lane < C) s += __expf(rowp[remBase + lane] - m);
    s = warp_sum(s);
    return m + __logf(s) - tv;
}

// Stage 1: fused CE + resonance; one plain partial store per block (no atomics:
// ~4.6K same-address atomicAdds measured ~35us serialization in R1/R3).
//   blocks [0, res_blocks)          : 1 edge/thread (R4 shape, best measured)
//   blocks [res_blocks, +ce_blocks) : 1 CE row/wave, max-pass logsumexp
//                                     (max-pass measured ~10us FASTER than
//                                     direct logsumexp across R4..R8 A/B),
//                                     NONTEMPORAL row loads (read-once; spare
//                                     L2 for the phase gathers), and x[t]
//                                     extracted from registers via shuffle
//                                     (kills the dependent rowp[t] load).
__global__ __launch_bounds__(256) void fused_kernel(
    const float* __restrict__ outputs,
    const int*   __restrict__ targets,
    const float* __restrict__ phase,
    const int*   __restrict__ esrc,
    const int*   __restrict__ edst,
    int B, int C, int N, int E,
    int res_blocks,
    float invB, float scaleE,
    float* __restrict__ ws)
{
    __shared__ float part[4];
    const int lane = threadIdx.x & 63;
    const int wave = threadIdx.x >> 6;

    float wsum = 0.0f;

    if ((int)blockIdx.x < res_blocks) {
        // ---------------- resonance path: one thread per edge ----------------
        const int i = blockIdx.x * blockDim.x + threadIdx.x;
        float d = 0.0f;
        if (i < E) {
            const int s = esrc[i];
            const int t = edst[i];
            const float a = phase[(size_t)s * (size_t)N + (size_t)t];
            const float b = phase[(size_t)t * (size_t)N + (size_t)s];
            d = fabsf(a - b);
            d = fmodf(d, TWO_PI_F);
            if (d > PI_F) d = TWO_PI_F - d;
        }
        d = warp_sum(d);
        if (lane == 0) wsum = d * scaleE;
    } else {
        // ---------------- CE path: one wave per row --------------------------
        const int row = (blockIdx.x - res_blocks) * 4 + wave;
        if (row < B) {
            const int nf4 = C >> 2;
            const int t = targets[row];              // wave-uniform scalar load
            const float* rowp = outputs + (size_t)row * (size_t)C;
            if (nf4 <= 256) {
                const f32x4* row4 = (const f32x4*)rowp;
                const f32x4 NEG = {-INFINITY, -INFINITY, -INFINITY, -INFINITY};
                const int j0 = lane, j1 = lane + 64, j2 = lane + 128, j3 = lane + 192;
                f32x4 v0 = (j0 < nf4) ? __builtin_nontemporal_load(row4 + j0) : NEG;
                f32x4 v1 = (j1 < nf4) ? __builtin_nontemporal_load(row4 + j1) : NEG;
                f32x4 v2 = (j2 < nf4) ? __builtin_nontemporal_load(row4 + j2) : NEG;
                f32x4 v3 = (j3 < nf4) ? __builtin_nontemporal_load(row4 + j3) : NEG;
                const int remBase = nf4 << 2;
                float tail = (remBase + lane < C)
                           ? __builtin_nontemporal_load(rowp + remBase + lane)
                           : -INFINITY;

                // ---- extract x[t] from registers (no dependent global load) ----
                const int fj   = t >> 2;             // all wave-uniform
                const int slot = t & 3;
                int owner;
                float cand;
                if (fj < nf4) {
                    owner = fj & 63;
                    const int reg = fj >> 6;         // 0..3
                    f32x4 c4 = (reg == 0) ? v0 : (reg == 1) ? v1 : (reg == 2) ? v2 : v3;
                    cand = (slot == 0) ? c4.x : (slot == 1) ? c4.y
                         : (slot == 2) ? c4.z : c4.w;
                } else {                             // target lives in the tail
                    owner = t - remBase;
                    cand = tail;
                }
                const float tv = __shfl(cand, owner, 64);

                float m = tail;
                m = fmaxf(m, max4(v0));
                m = fmaxf(m, max4(v1));
                m = fmaxf(m, max4(v2));
                m = fmaxf(m, max4(v3));
                m = warp_max(m);

                float s;
                s  = __expf(v0.x - m) + __expf(v0.y - m) + __expf(v0.z - m) + __expf(v0.w - m);
                s += __expf(v1.x - m) + __expf(v1.y - m) + __expf(v1.z - m) + __expf(v1.w - m);
                s += __expf(v2.x - m) + __expf(v2.y - m) + __expf(v2.z - m) + __expf(v2.w - m);
                s += __expf(v3.x - m) + __expf(v3.y - m) + __expf(v3.z - m) + __expf(v3.w - m);
                s += __expf(tail - m);
                s = warp_sum(s);

                if (lane == 0) wsum = (m + __logf(s) - tv) * invB;
            } else {
                const float c = ce_row_generic(rowp, C, lane, t);
                if (lane == 0) wsum = c * invB;
            }
        }
    }

    if (lane == 0) part[wave] = wsum;
    __syncthreads();
    if (threadIdx.x == 0)
        ws[blockIdx.x] = part[0] + part[1] + part[2] + part[3];   // plain store
}

// Stage 2: single block reduces all partials and writes the scalar output.
__global__ __launch_bounds__(256) void reduce_kernel(
    const float* __restrict__ ws, int P, float* __restrict__ out)
{
    float s = 0.0f;
    for (int i = threadIdx.x; i < P; i += 256)
        s += ws[i];
    s = warp_sum(s);
    __shared__ float part[4];
    if ((threadIdx.x & 63) == 0) part[threadIdx.x >> 6] = s;
    __syncthreads();
    if (threadIdx.x == 0)
        out[0] = part[0] + part[1] + part[2] + part[3];
}

extern "C" void kernel_launch(void* const* d_in, const int* in_sizes, int n_in,
                              void* d_out, int out_size, void* d_ws, size_t ws_size,
                              hipStream_t stream) {
    const float* outputs = (const float*)d_in[0];
    const int*   targets = (const int*)d_in[1];
    const float* phase   = (const float*)d_in[2];
    const int*   esrc    = (const int*)d_in[3];
    const int*   edst    = (const int*)d_in[4];

    const int B = in_sizes[1];
    const int C = in_sizes[0] / B;
    const int E = in_sizes[3];
    int N = 1;
    while ((long long)N * (long long)N < (long long)in_sizes[2]) N++;

    const int res_blocks = (E + 255) / 256;          // 512
    const int ce_blocks  = (B + 3) / 4;              // 4096
    const int grid = res_blocks + ce_blocks;         // 4608 partials

    float* ws = (float*)d_ws;

    fused_kernel<<<grid, 256, 0, stream>>>(outputs, targets, phase, esrc, edst,
                                           B, C, N, E, res_blocks,
                                           1.0f / (float)B, 0.1f / (float)E,
                                           ws);
    reduce_kernel<<<1, 256, 0, stream>>>(ws, grid, (float*)d_out);
}

// Round 10
// 143.127 us; speedup vs baseline: 1.1151x; 1.0162x over previous
//
#include <hip/hip_runtime.h>
#include <math.h>

#define TWO_PI_F 6.28318530717958647692f
#define PI_F     3.14159265358979323846f
#define CE_ROWS  4   // rows per wave, software-pipelined

typedef float f32x4 __attribute__((ext_vector_type(4)));

__device__ __forceinline__ float warp_sum(float s) {
    #pragma unroll
    for (int off = 32; off; off >>= 1) s += __shfl_xor(s, off, 64);
    return s;
}
__device__ __forceinline__ float warp_max(float m) {
    #pragma unroll
    for (int off = 32; off; off >>= 1) m = fmaxf(m, __shfl_xor(m, off, 64));
    return m;
}
__device__ __forceinline__ float max4(f32x4 v) {
    return fmaxf(fmaxf(v.x, v.y), fmaxf(v.z, v.w));
}

// One row's -log_softmax[t] from a register-resident row. All-lane uniform result.
__device__ __forceinline__ float ce_compute(f32x4 v0, f32x4 v1, f32x4 v2, f32x4 v3,
                                            float tail, int t, int nf4, int remBase,
                                            int lane) {
    // extract x[t] from registers (no dependent global load) — R9 verified win
    const int fj   = t >> 2;
    const int slot = t & 3;
    int owner;
    float cand;
    if (fj < nf4) {
        owner = fj & 63;
        const int reg = fj >> 6;
        f32x4 c4 = (reg == 0) ? v0 : (reg == 1) ? v1 : (reg == 2) ? v2 : v3;
        cand = (slot == 0) ? c4.x : (slot == 1) ? c4.y : (slot == 2) ? c4.z : c4.w;
    } else {
        owner = t - remBase;
        cand = tail;
    }
    const float tv = __shfl(cand, owner, 64);

    float m = tail;
    m = fmaxf(m, max4(v0));
    m = fmaxf(m, max4(v1));
    m = fmaxf(m, max4(v2));
    m = fmaxf(m, max4(v3));
    m = warp_max(m);           // max-pass kept: measured ~10us faster than no-max

    float s;
    s  = __expf(v0.x - m) + __expf(v0.y - m) + __expf(v0.z - m) + __expf(v0.w - m);
    s += __expf(v1.x - m) + __expf(v1.y - m) + __expf(v1.z - m) + __expf(v1.w - m);
    s += __expf(v2.x - m) + __expf(v2.y - m) + __expf(v2.z - m) + __expf(v2.w - m);
    s += __expf(v3.x - m) + __expf(v3.y - m) + __expf(v3.z - m) + __expf(v3.w - m);
    s += __expf(tail - m);
    s = warp_sum(s);

    return m + __logf(s) - tv;
}

// Generic CE fallback (C > 1024): two passes with max subtraction.
__device__ float ce_row_generic(const float* __restrict__ rowp, int C, int lane, int t) {
    const float4* row4 = (const float4*)rowp;
    const int nf4 = C >> 2;
    const float tv = rowp[t];
    float m = -INFINITY;
    for (int j = lane; j < nf4; j += 64) {
        float4 x = row4[j];
        m = fmaxf(m, fmaxf(fmaxf(x.x, x.y), fmaxf(x.z, x.w)));
    }
    const int remBase = nf4 << 2;
    if (remBase + lane < C) m = fmaxf(m, rowp[remBase + lane]);
    m = warp_max(m);
    float s = 0.0f;
    for (int j = lane; j < nf4; j += 64) {
        float4 x = row4[j];
        s += __expf(x.x - m) + __expf(x.y - m) + __expf(x.z - m) + __expf(x.w - m);
    }
    if (remBase + lane < C) s += __expf(rowp[remBase + lane] - m);
    s = warp_sum(s);
    return m + __logf(s) - tv;
}

// Stage 1: fused CE + resonance; one plain partial store per block (no atomics).
//   blocks [0, res_blocks)          : 1 edge/thread (best measured shape)
//   blocks [res_blocks, +ce_blocks) : CE_ROWS consecutive rows per wave,
//                                     SOFTWARE-PIPELINED: row k+1's loads are
//                                     issued into a second register buffer
//                                     before row k's reductions — keeps 4KB/wave
//                                     continuously in flight instead of a
//                                     load-stall-compute-retire duty cycle.
__global__ __launch_bounds__(256) void fused_kernel(
    const float* __restrict__ outputs,
    const int*   __restrict__ targets,
    const float* __restrict__ phase,
    const int*   __restrict__ esrc,
    const int*   __restrict__ edst,
    int B, int C, int N, int E,
    int res_blocks,
    float invB, float scaleE,
    float* __restrict__ ws)
{
    __shared__ float part[4];
    const int lane = threadIdx.x & 63;
    const int wave = threadIdx.x >> 6;

    float wsum = 0.0f;

    if ((int)blockIdx.x < res_blocks) {
        // ---------------- resonance path: one thread per edge ----------------
        const int i = blockIdx.x * blockDim.x + threadIdx.x;
        float d = 0.0f;
        if (i < E) {
            const int s = esrc[i];
            const int t = edst[i];
            const float a = phase[(size_t)s * (size_t)N + (size_t)t];
            const float b = phase[(size_t)t * (size_t)N + (size_t)s];
            d = fabsf(a - b);
            d = fmodf(d, TWO_PI_F);
            if (d > PI_F) d = TWO_PI_F - d;
        }
        d = warp_sum(d);
        if (lane == 0) wsum = d * scaleE;
    } else {
        // ---------------- CE path: CE_ROWS rows per wave, pipelined ----------
        const int nf4 = C >> 2;
        const int wbase = (((int)blockIdx.x - res_blocks) * 4 + wave) * CE_ROWS;
        if (wbase < B) {
            if (nf4 <= 256) {
                const int remBase = nf4 << 2;
                const int j0 = lane, j1 = lane + 64, j2 = lane + 128, j3 = lane + 192;
                const f32x4 NEG = {-INFINITY, -INFINITY, -INFINITY, -INFINITY};

                // prime buffer A with row wbase
                const float* rp = outputs + (size_t)wbase * (size_t)C;
                const f32x4* r4 = (const f32x4*)rp;
                f32x4 a0 = (j0 < nf4) ? __builtin_nontemporal_load(r4 + j0) : NEG;
                f32x4 a1 = (j1 < nf4) ? __builtin_nontemporal_load(r4 + j1) : NEG;
                f32x4 a2 = (j2 < nf4) ? __builtin_nontemporal_load(r4 + j2) : NEG;
                f32x4 a3 = (j3 < nf4) ? __builtin_nontemporal_load(r4 + j3) : NEG;
                float atail = (remBase + lane < C)
                            ? __builtin_nontemporal_load(rp + remBase + lane)
                            : -INFINITY;
                int   at = targets[wbase];

                float acc = 0.0f;
                #pragma unroll
                for (int k = 0; k < CE_ROWS; ++k) {
                    const int row = wbase + k;
                    // prefetch row k+1 into buffer B (issued before compute)
                    f32x4 b0 = NEG, b1 = NEG, b2 = NEG, b3 = NEG;
                    float btail = -INFINITY;
                    int   bt = 0;
                    if (k + 1 < CE_ROWS && row + 1 < B) {
                        const float* np = outputs + (size_t)(row + 1) * (size_t)C;
                        const f32x4* n4 = (const f32x4*)np;
                        bt = targets[row + 1];
                        if (j0 < nf4) b0 = __builtin_nontemporal_load(n4 + j0);
                        if (j1 < nf4) b1 = __builtin_nontemporal_load(n4 + j1);
                        if (j2 < nf4) b2 = __builtin_nontemporal_load(n4 + j2);
                        if (j3 < nf4) b3 = __builtin_nontemporal_load(n4 + j3);
                        if (remBase + lane < C)
                            btail = __builtin_nontemporal_load(np + remBase + lane);
                    }
                    if (row < B)
                        acc += ce_compute(a0, a1, a2, a3, atail, at, nf4, remBase, lane);
                    // rotate B -> A (register renames under full unroll)
                    a0 = b0; a1 = b1; a2 = b2; a3 = b3; atail = btail; at = bt;
                }
                if (lane == 0) wsum = acc * invB;
            } else {
                float acc = 0.0f;
                for (int k = 0; k < CE_ROWS; ++k) {
                    const int row = wbase + k;
                    if (row < B)
                        acc += ce_row_generic(outputs + (size_t)row * (size_t)C,
                                              C, lane, targets[row]);
                }
                if (lane == 0) wsum = acc * invB;
            }
        }
    }

    if (lane == 0) part[wave] = wsum;
    __syncthreads();
    if (threadIdx.x == 0)
        ws[blockIdx.x] = part[0] + part[1] + part[2] + part[3];   // plain store
}

// Stage 2: single block (512 threads) reduces all partials.
__global__ __launch_bounds__(512) void reduce_kernel(
    const float* __restrict__ ws, int P, float* __restrict__ out)
{
    float s = 0.0f;
    for (int i = threadIdx.x; i < P; i += 512)
        s += ws[i];
    s = warp_sum(s);
    __shared__ float part[8];
    if ((threadIdx.x & 63) == 0) part[threadIdx.x >> 6] = s;
    __syncthreads();
    if (threadIdx.x == 0) {
        float tot = 0.0f;
        #pragma unroll
        for (int i = 0; i < 8; i++) tot += part[i];
        out[0] = tot;
    }
}

extern "C" void kernel_launch(void* const* d_in, const int* in_sizes, int n_in,
                              void* d_out, int out_size, void* d_ws, size_t ws_size,
                              hipStream_t stream) {
    const float* outputs = (const float*)d_in[0];
    const int*   targets = (const int*)d_in[1];
    const float* phase   = (const float*)d_in[2];
    const int*   esrc    = (const int*)d_in[3];
    const int*   edst    = (const int*)d_in[4];

    const int B = in_sizes[1];
    const int C = in_sizes[0] / B;
    const int E = in_sizes[3];
    int N = 1;
    while ((long long)N * (long long)N < (long long)in_sizes[2]) N++;

    const int res_blocks = (E + 255) / 256;                  // 512
    const int rows_per_block = 4 * CE_ROWS;                  // 16
    const int ce_blocks  = (B + rows_per_block - 1) / rows_per_block;  // 1024
    const int grid = res_blocks + ce_blocks;                 // 1536 partials

    float* ws = (float*)d_ws;

    fused_kernel<<<grid, 256, 0, stream>>>(outputs, targets, phase, esrc, edst,
                                           B, C, N, E, res_blocks,
                                           1.0f / (float)B, 0.1f / (float)E,
                                           ws);
    reduce_kernel<<<1, 512, 0, stream>>>(ws, grid, (float*)d_out);
}

// Round 11
// 142.816 us; speedup vs baseline: 1.1175x; 1.0022x over previous
//
#include <hip/hip_runtime.h>
#include <math.h>

#define TWO_PI_F 6.28318530717958647692f
#define PI_F     3.14159265358979323846f
#define CE_ROWS  4   // rows per wave, ALL loads issued up front

typedef float f32x4 __attribute__((ext_vector_type(4)));

__device__ __forceinline__ float warp_sum(float s) {
    #pragma unroll
    for (int off = 32; off; off >>= 1) s += __shfl_xor(s, off, 64);
    return s;
}
__device__ __forceinline__ float warp_max(float m) {
    #pragma unroll
    for (int off = 32; off; off >>= 1) m = fmaxf(m, __shfl_xor(m, off, 64));
    return m;
}
__device__ __forceinline__ float max4(f32x4 v) {
    return fmaxf(fmaxf(v.x, v.y), fmaxf(v.z, v.w));
}

// One row's -log_softmax[t] from a register-resident row. Wave-uniform result.
__device__ __forceinline__ float ce_compute(f32x4 v0, f32x4 v1, f32x4 v2, f32x4 v3,
                                            float tail, int t, int nf4, int remBase,
                                            int lane) {
    // extract x[t] from registers (no dependent global load) — R9 verified win
    const int fj   = t >> 2;
    const int slot = t & 3;
    int owner;
    float cand;
    if (fj < nf4) {
        owner = fj & 63;
        const int reg = fj >> 6;
        f32x4 c4 = (reg == 0) ? v0 : (reg == 1) ? v1 : (reg == 2) ? v2 : v3;
        cand = (slot == 0) ? c4.x : (slot == 1) ? c4.y : (slot == 2) ? c4.z : c4.w;
    } else {
        owner = t - remBase;
        cand = tail;
    }
    const float tv = __shfl(cand, owner, 64);

    float m = tail;
    m = fmaxf(m, max4(v0));
    m = fmaxf(m, max4(v1));
    m = fmaxf(m, max4(v2));
    m = fmaxf(m, max4(v3));
    m = warp_max(m);           // max-pass kept: measured ~10us faster than no-max

    float s;
    s  = __expf(v0.x - m) + __expf(v0.y - m) + __expf(v0.z - m) + __expf(v0.w - m);
    s += __expf(v1.x - m) + __expf(v1.y - m) + __expf(v1.z - m) + __expf(v1.w - m);
    s += __expf(v2.x - m) + __expf(v2.y - m) + __expf(v2.z - m) + __expf(v2.w - m);
    s += __expf(v3.x - m) + __expf(v3.y - m) + __expf(v3.z - m) + __expf(v3.w - m);
    s += __expf(tail - m);
    s = warp_sum(s);

    return m + __logf(s) - tv;
}

// Generic CE fallback (C > 1024): two passes with max subtraction.
__device__ float ce_row_generic(const float* __restrict__ rowp, int C, int lane, int t) {
    const float4* row4 = (const float4*)rowp;
    const int nf4 = C >> 2;
    const float tv = rowp[t];
    float m = -INFINITY;
    for (int j = lane; j < nf4; j += 64) {
        float4 x = row4[j];
        m = fmaxf(m, fmaxf(fmaxf(x.x, x.y), fmaxf(x.z, x.w)));
    }
    const int remBase = nf4 << 2;
    if (remBase + lane < C) m = fmaxf(m, rowp[remBase + lane]);
    m = warp_max(m);
    float s = 0.0f;
    for (int j = lane; j < nf4; j += 64) {
        float4 x = row4[j];
        s += __expf(x.x - m) + __expf(x.y - m) + __expf(x.z - m) + __expf(x.w - m);
    }
    if (remBase + lane < C) s += __expf(rowp[remBase + lane] - m);
    s = warp_sum(s);
    return m + __logf(s) - tv;
}

// issue one row's loads into named regs (nontemporal: read-once streaming)
#define LOAD_ROW(rowidx, V0, V1, V2, V3, VT)                                   \
    {                                                                          \
        const float* _p = outputs + (size_t)(rowidx) * (size_t)C;              \
        const f32x4* _q = (const f32x4*)_p;                                    \
        V0 = (j0 < nf4) ? __builtin_nontemporal_load(_q + j0) : NEG;           \
        V1 = (j1 < nf4) ? __builtin_nontemporal_load(_q + j1) : NEG;           \
        V2 = (j2 < nf4) ? __builtin_nontemporal_load(_q + j2) : NEG;           \
        V3 = (j3 < nf4) ? __builtin_nontemporal_load(_q + j3) : NEG;           \
        VT = (remBase + lane < C)                                              \
           ? __builtin_nontemporal_load(_p + remBase + lane) : -INFINITY;      \
    }

// Stage 1: fused CE + resonance; one plain partial store per block (no atomics:
// ~4.6K same-address atomicAdds measured ~35us serialization in R1/R3).
//   blocks [0, res_blocks)          : 1 edge/thread (best measured shape)
//   blocks [res_blocks, +ce_blocks) : 4 rows/wave, ALL 16 dwordx4 loads issued
//                                     before any compute (256B/lane in flight,
//                                     2x the R10 1-deep pipeline that won).
__global__ __launch_bounds__(256) void fused_kernel(
    const float* __restrict__ outputs,
    const int*   __restrict__ targets,
    const float* __restrict__ phase,
    const int*   __restrict__ esrc,
    const int*   __restrict__ edst,
    int B, int C, int N, int E,
    int res_blocks,
    float invB, float scaleE,
    float* __restrict__ ws)
{
    __shared__ float part[4];
    const int lane = threadIdx.x & 63;
    const int wave = threadIdx.x >> 6;

    float wsum = 0.0f;

    if ((int)blockIdx.x < res_blocks) {
        // ---------------- resonance path: one thread per edge ----------------
        const int i = blockIdx.x * blockDim.x + threadIdx.x;
        float d = 0.0f;
        if (i < E) {
            const int s = esrc[i];
            const int t = edst[i];
            const float a = phase[(size_t)s * (size_t)N + (size_t)t];
            const float b = phase[(size_t)t * (size_t)N + (size_t)s];
            d = fabsf(a - b);
            d = fmodf(d, TWO_PI_F);
            if (d > PI_F) d = TWO_PI_F - d;
        }
        d = warp_sum(d);
        if (lane == 0) wsum = d * scaleE;
    } else {
        // ---------------- CE path: 4 rows/wave, all loads up front -----------
        const int nf4 = C >> 2;
        const int wbase = (((int)blockIdx.x - res_blocks) * 4 + wave) * CE_ROWS;
        if (wbase < B) {
            if (nf4 <= 256 && wbase + CE_ROWS <= B) {
                const int remBase = nf4 << 2;
                const int j0 = lane, j1 = lane + 64, j2 = lane + 128, j3 = lane + 192;
                const f32x4 NEG = {-INFINITY, -INFINITY, -INFINITY, -INFINITY};

                // one 16B load for 4 targets (wbase is a multiple of 4)
                const int4 t4 = *(const int4*)(targets + wbase);

                f32x4 a0, a1, a2, a3; float at;
                f32x4 b0, b1, b2, b3; float bt;
                f32x4 c0, c1, c2, c3; float ct;
                f32x4 d0, d1, d2, d3; float dt;
                LOAD_ROW(wbase + 0, a0, a1, a2, a3, at);
                LOAD_ROW(wbase + 1, b0, b1, b2, b3, bt);
                LOAD_ROW(wbase + 2, c0, c1, c2, c3, ct);
                LOAD_ROW(wbase + 3, d0, d1, d2, d3, dt);

                float acc;
                acc  = ce_compute(a0, a1, a2, a3, at, t4.x, nf4, remBase, lane);
                acc += ce_compute(b0, b1, b2, b3, bt, t4.y, nf4, remBase, lane);
                acc += ce_compute(c0, c1, c2, c3, ct, t4.z, nf4, remBase, lane);
                acc += ce_compute(d0, d1, d2, d3, dt, t4.w, nf4, remBase, lane);

                if (lane == 0) wsum = acc * invB;
            } else {
                float acc = 0.0f;
                for (int k = 0; k < CE_ROWS; ++k) {
                    const int row = wbase + k;
                    if (row < B)
                        acc += ce_row_generic(outputs + (size_t)row * (size_t)C,
                                              C, lane, targets[row]);
                }
                if (lane == 0) wsum = acc * invB;
            }
        }
    }

    if (lane == 0) part[wave] = wsum;
    __syncthreads();
    if (threadIdx.x == 0)
        ws[blockIdx.x] = part[0] + part[1] + part[2] + part[3];   // plain store
}

// Stage 2: single block (512 threads) reduces all partials.
__global__ __launch_bounds__(512) void reduce_kernel(
    const float* __restrict__ ws, int P, float* __restrict__ out)
{
    float s = 0.0f;
    for (int i = threadIdx.x; i < P; i += 512)
        s += ws[i];
    s = warp_sum(s);
    __shared__ float part[8];
    if ((threadIdx.x & 63) == 0) part[threadIdx.x >> 6] = s;
    __syncthreads();
    if (threadIdx.x == 0) {
        float tot = 0.0f;
        #pragma unroll
        for (int i = 0; i < 8; i++) tot += part[i];
        out[0] = tot;
    }
}

extern "C" void kernel_launch(void* const* d_in, const int* in_sizes, int n_in,
                              void* d_out, int out_size, void* d_ws, size_t ws_size,
                              hipStream_t stream) {
    const float* outputs = (const float*)d_in[0];
    const int*   targets = (const int*)d_in[1];
    const float* phase   = (const float*)d_in[2];
    const int*   esrc    = (const int*)d_in[3];
    const int*   edst    = (const int*)d_in[4];

    const int B = in_sizes[1];
    const int C = in_sizes[0] / B;
    const int E = in_sizes[3];
    int N = 1;
    while ((long long)N * (long long)N < (long long)in_sizes[2]) N++;

    const int res_blocks = (E + 255) / 256;                  // 512
    const int rows_per_block = 4 * CE_ROWS;                  // 16
    const int ce_blocks  = (B + rows_per_block - 1) / rows_per_block;  // 1024
    const int grid = res_blocks + ce_blocks;                 // 1536 partials

    float* ws = (float*)d_ws;

    fused_kernel<<<grid, 256, 0, stream>>>(outputs, targets, phase, esrc, edst,
                                           B, C, N, E, res_blocks,
                                           1.0f / (float)B, 0.1f / (float)E,
                                           ws);
    reduce_kernel<<<1, 512, 0, stream>>>(ws, grid, (float*)d_out);
}